// Round 2
// baseline (1160.914 us; speedup 1.0000x reference)
//
#include <hip/hip_runtime.h>

typedef __bf16 bf16x8 __attribute__((ext_vector_type(8)));
typedef float f32x4 __attribute__((ext_vector_type(4)));

#define MFMA16(a, b, c) __builtin_amdgcn_mfma_f32_16x16x32_bf16(a, b, c, 0, 0, 0)

// async global->LDS, 16B per lane; LDS dest is wave-uniform base + lane*16
__device__ __forceinline__ void gload_lds16(const void* g, void* l) {
  __builtin_amdgcn_global_load_lds(
      (const __attribute__((address_space(1))) void*)(unsigned long long)g,
      (__attribute__((address_space(3))) void*)(unsigned int)(unsigned long long)l,
      16, 0, 0);
}

// ---------------- K0: convert 3x512x512 fp32 weights -> bf16 ----------------
__global__ void cvt_w_kernel(const float* __restrict__ wq, const float* __restrict__ wk,
                             const float* __restrict__ wv, __bf16* __restrict__ w) {
  int i = blockIdx.x * 256 + threadIdx.x;  // grid 1024 -> 262144
  w[i]          = (__bf16)wq[i];
  w[i + 262144] = (__bf16)wk[i];
  w[i + 524288] = (__bf16)wv[i];
}

// ---------------- K1: LayerNorm rows of 512, fp32 -> bf16 -------------------
// input rows in (b,t,n) order; output rows PERMUTED to (b,n,t) order so the
// QKV GEMM can emit (b,n,h,t,d)-contiguous tensors for attention.
__global__ __launch_bounds__(256) void ln_kernel(
    const float* __restrict__ x, const float* __restrict__ cx,
    const float* __restrict__ g, const float* __restrict__ bet,
    __bf16* __restrict__ xn) {
  int wave = threadIdx.x >> 6, lane = threadIdx.x & 63;
  long row = (long)blockIdx.x * 4 + wave;
  int rloc = (row < 98304) ? (int)row : (int)(row - 98304);
  const float* src = (row < 98304) ? (x + row * 512) : (cx + (long)rloc * 512);
  const f32x4* p = (const f32x4*)(src + lane * 8);
  f32x4 a = p[0], b = p[1];
  float s  = a[0] + a[1] + a[2] + a[3] + b[0] + b[1] + b[2] + b[3];
  float s2 = a[0]*a[0] + a[1]*a[1] + a[2]*a[2] + a[3]*a[3]
           + b[0]*b[0] + b[1]*b[1] + b[2]*b[2] + b[3]*b[3];
  for (int d = 1; d < 64; d <<= 1) { s += __shfl_xor(s, d, 64); s2 += __shfl_xor(s2, d, 64); }
  float mean = s * (1.0f / 512.0f);
  float var  = s2 * (1.0f / 512.0f) - mean * mean;
  float rs = rsqrtf(var + 1e-5f);
  const f32x4* gp = (const f32x4*)(g + lane * 8);
  const f32x4* bp = (const f32x4*)(bet + lane * 8);
  f32x4 g0 = gp[0], g1 = gp[1], b0 = bp[0], b1 = bp[1];
  bf16x8 o;
  for (int j = 0; j < 4; ++j) o[j]     = (__bf16)((a[j] - mean) * rs * g0[j] + b0[j]);
  for (int j = 0; j < 4; ++j) o[4 + j] = (__bf16)((b[j] - mean) * rs * g1[j] + b1[j]);
  // permute (b,t,n) -> (b,n,t)
  int b_ = rloc / 6144;
  int rem = rloc - b_ * 6144;
  int t_ = rem / 24;
  int n_ = rem - t_ * 24;
  long drow = (long)(b_ * 24 + n_) * 256 + t_ + ((row < 98304) ? 0 : 98304);
  *(bf16x8*)(xn + drow * 512 + lane * 8) = o;
}

// ---------------- K2: QKV projection GEMM (NT), 128x128 tile, BK=64 ---------
// z=0: Q = xn @ Wq^T ; z=1: K = cn @ Wk^T ; z=2: V = cn @ Wv^T
// A rows are in (b,n,t) order; epilogue splits col=(h,d) and writes
// C in (b,n,h,t,d) layout: addr = ((m>>8)*8+h)*16384 + (m&255)*64 + d.
__global__ __launch_bounds__(256) void gemm_qkv_kernel(
    const __bf16* __restrict__ act, const __bf16* __restrict__ w,
    __bf16* __restrict__ outqkv) {
  int z = blockIdx.z;
  const __bf16* A = act + (z ? (long)50331648 : 0);   // cn for K,V
  const __bf16* B = w + (long)z * 262144;
  __bf16* C = outqkv + (long)z * 50331648;
  int m0 = blockIdx.x * 128, n0 = blockIdx.y * 128;
  int tid = threadIdx.x, wave = tid >> 6, lane = tid & 63;
  int q4 = lane >> 4, cl = lane & 15;
  int wm = wave & 1, wn = wave >> 1;
  __shared__ __bf16 As[128 * 64];
  __shared__ __bf16 Bs[128 * 64];
  f32x4 acc[4][4] = {};
  for (int kb = 0; kb < 512; kb += 64) {
    for (int i = 0; i < 4; ++i) {
      int t = i * 256 + tid;
      int row = t >> 3;
      int col = (t & 7) * 8;
      gload_lds16(A + (long)(m0 + row) * 512 + kb + col, (char*)As + (i * 256 + wave * 64) * 16);
      gload_lds16(B + (long)(n0 + row) * 512 + kb + col, (char*)Bs + (i * 256 + wave * 64) * 16);
    }
    __syncthreads();
    for (int kc = 0; kc < 2; ++kc) {
      bf16x8 af[4], bfr[4];
      for (int mt = 0; mt < 4; ++mt)
        af[mt] = *(const bf16x8*)(As + (wm * 64 + mt * 16 + cl) * 64 + kc * 32 + q4 * 8);
      for (int nt = 0; nt < 4; ++nt)
        bfr[nt] = *(const bf16x8*)(Bs + (wn * 64 + nt * 16 + cl) * 64 + kc * 32 + q4 * 8);
      for (int mt = 0; mt < 4; ++mt)
        for (int nt = 0; nt < 4; ++nt)
          acc[mt][nt] = MFMA16(af[mt], bfr[nt], acc[mt][nt]);
    }
    __syncthreads();
  }
  for (int mt = 0; mt < 4; ++mt)
    for (int nt = 0; nt < 4; ++nt) {
      int col = n0 + wn * 64 + nt * 16 + cl;
      int hh = col >> 6, dd = col & 63;
      int mbase = m0 + wm * 64 + mt * 16 + q4 * 4;
      for (int r = 0; r < 4; ++r) {
        int m = mbase + r;
        long addr = ((long)((m >> 8) * 8 + hh) << 14) + ((m & 255) << 6) + dd;
        C[addr] = (__bf16)acc[mt][nt][r];
      }
    }
}

// ---------------- K3: attention + softmax + residual + output ---------------
// one block per (b,n,h); Q/K/V contiguous 256x64 bf16 slabs per block.
// Swapped QK^T (A=K, B=Q) -> P^T layout: softmax fully in-register, and the
// P fragments feed PV's A-operand directly (k-axis permutation absorbed into
// the V^T LDS column order). One __syncthreads() total.
__global__ __launch_bounds__(256) void attn_kernel(
    const __bf16* __restrict__ Q, const __bf16* __restrict__ K,
    const __bf16* __restrict__ V, const float* __restrict__ x,
    float* __restrict__ out) {
  int blk = blockIdx.x;            // (b*24+n)*8 + h, 3072 total
  int h = blk & 7;
  int bn = blk >> 3;
  int n_ = bn % 24;
  int b_ = bn / 24;
  const __bf16* Qh = Q + (long)blk * 16384;
  const __bf16* Kh = K + (long)blk * 16384;
  const __bf16* Vh = V + (long)blk * 16384;
  long xbase = (long)b_ * 3145728 + (long)n_ * 512 + h * 64;  // + t*12288 + d

  int tid = threadIdx.x, wave = tid >> 6, lane = tid & 63;
  int q4 = lane >> 4, cl = lane & 15;

  __shared__ __bf16 Ks[256 * 64];  // row-major [key][64], 16B-chunk XOR swizzled
  __shared__ __bf16 Vt[64 * 256];  // V^T [d][perm(key)], 16B-chunk XOR swizzled

  // ---- stage K via global_load_lds: linear LDS dest, pre-swizzled source
  {
    int c = lane & 7;
    int r8 = lane >> 3;
    for (int it = 0; it < 8; ++it) {
      int row = wave * 64 + it * 8 + r8;
      gload_lds16(Kh + row * 64 + ((c ^ (row & 7)) << 3),
                  (char*)Ks + (wave * 64 + it * 8) * 128);
    }
  }
  // ---- stage V transposed + key-permuted; thread handles key = tid
  {
    int key = tid;
    // within each 32-key chunk: key = q4*4 + half*16 + j  ->  col = q4*8 + half*4 + j
    int colp = (key & ~31) | ((key & 12) << 1) | ((key & 16) >> 2) | (key & 3);
    const __bf16* vrow = Vh + key * 64;
    for (int i = 0; i < 8; ++i) {
      bf16x8 v = *(const bf16x8*)(vrow + i * 8);
      for (int j = 0; j < 8; ++j) {
        int d = i * 8 + j;
        *(__bf16*)((char*)Vt + d * 512 + ((colp * 2) ^ ((d & 7) << 4))) = v[j];
      }
    }
  }
  __syncthreads();

  const float c_exp = 0.125f * 1.44269504088896f;  // fold 1/sqrt(64) into exp2
  for (int iter = 0; iter < 4; ++iter) {
    int qt = wave * 4 + iter;  // 16 queries per iter per wave
    const __bf16* qrow = Qh + (qt * 16 + cl) * 64 + q4 * 8;
    bf16x8 qb0 = *(const bf16x8*)(qrow);
    bf16x8 qb1 = *(const bf16x8*)(qrow + 32);
    f32x4 s[16];
#pragma unroll
    for (int kt = 0; kt < 16; ++kt) {
      int row = kt * 16 + cl;
      const char* kb = (const char*)Ks + row * 128;
      bf16x8 ka0 = *(const bf16x8*)(kb + ((q4 ^ (row & 7)) << 4));
      bf16x8 ka1 = *(const bf16x8*)(kb + (((4 + q4) ^ (row & 7)) << 4));
      f32x4 a = {};
      a = MFMA16(ka0, qb0, a);   // A=K, B=Q -> D[key][q]
      a = MFMA16(ka1, qb1, a);
      s[kt] = a;
    }
    // softmax over keys for query q = cl; lane holds keys kt*16+q4*4+r
    float mx = -1e30f;
#pragma unroll
    for (int kt = 0; kt < 16; ++kt)
#pragma unroll
      for (int r = 0; r < 4; ++r) mx = fmaxf(mx, s[kt][r]);
    mx = fmaxf(mx, __shfl_xor(mx, 16, 64));
    mx = fmaxf(mx, __shfl_xor(mx, 32, 64));
    float lsum = 0.0f;
#pragma unroll
    for (int kt = 0; kt < 16; ++kt)
#pragma unroll
      for (int r = 0; r < 4; ++r) {
        float p = exp2f((s[kt][r] - mx) * c_exp);
        s[kt][r] = p;
        lsum += p;
      }
    lsum += __shfl_xor(lsum, 16, 64);
    lsum += __shfl_xor(lsum, 32, 64);

    // PV: 8 key-chunks of 32; P already in A-frag layout (keys permuted to
    // match Vt's column order), V^T from swizzled LDS.
    f32x4 o[4] = {};
#pragma unroll
    for (int m = 0; m < 8; ++m) {
      bf16x8 pa;
#pragma unroll
      for (int j = 0; j < 4; ++j) {
        pa[j]     = (__bf16)s[2 * m][j];
        pa[4 + j] = (__bf16)s[2 * m + 1][j];
      }
#pragma unroll
      for (int db = 0; db < 4; ++db) {
        int row = db * 16 + cl;
        bf16x8 vb = *(const bf16x8*)((const char*)Vt + row * 512 +
                                     (((m * 4 + q4) ^ (row & 7)) << 4));
        o[db] = MFMA16(pa, vb, o[db]);
      }
    }
    // epilogue: normalize, residual, store (original (b,t,n,c) layout)
#pragma unroll
    for (int r = 0; r < 4; ++r) {
      float lr = __shfl(lsum, q4 * 4 + r, 64);
      float inv = 1.0f / lr;
      long trow = xbase + (long)(qt * 16 + q4 * 4 + r) * 12288;
#pragma unroll
      for (int db = 0; db < 4; ++db) {
        long addr = trow + db * 16 + cl;
        out[addr] = x[addr] + o[db][r] * inv;
      }
    }
  }
}

extern "C" void kernel_launch(void* const* d_in, const int* in_sizes, int n_in,
                              void* d_out, int out_size, void* d_ws, size_t ws_size,
                              hipStream_t stream) {
  const float* x     = (const float*)d_in[0];
  const float* cx    = (const float*)d_in[1];
  const float* gamma = (const float*)d_in[2];
  const float* beta  = (const float*)d_in[3];
  const float* Wq    = (const float*)d_in[4];
  const float* Wk    = (const float*)d_in[5];
  const float* Wv    = (const float*)d_in[6];
  float* out = (float*)d_out;
  char* ws = (char*)d_ws;

  // workspace layout (bytes):
  //   [0,            1572864)   Wqkv bf16  (3*512*512*2)
  //   [1572864,      202899456) xn|cn bf16 (2*98304*512*2), rows in (b,n,t)
  //   [202899456,    504889344) Q|K|V bf16 (3*98304*512*2), (b,n,h,t,d)
  __bf16* Wb = (__bf16*)(ws);
  __bf16* xn = (__bf16*)(ws + 1572864);
  __bf16* Qb = (__bf16*)(ws + 202899456);

  cvt_w_kernel<<<1024, 256, 0, stream>>>(Wq, Wk, Wv, Wb);
  ln_kernel<<<49152, 256, 0, stream>>>(x, cx, gamma, beta, xn);
  gemm_qkv_kernel<<<dim3(768, 4, 3), 256, 0, stream>>>(xn, Wb, Qb);
  attn_kernel<<<3072, 256, 0, stream>>>(Qb, Qb + 50331648, Qb + 100663296, x, out);
}